// Round 1
// baseline (2921.938 us; speedup 1.0000x reference)
//
#include <hip/hip_runtime.h>
#include <cmath>

// Problem constants (B=8, C=512, L=2048, Cr=C/8=64)
#define LL  2048
#define CIN 512
#define CR  64

// ---------------------------------------------------------------------------
// Projection: Out[b,o,i] = sum_c W[o,c] * X[b,c,i] + Bias[o]
// LDS-tiled 64(o) x 64(i) tile, K-step 32. 256 threads, 4x4 micro-tile/thread.
// ---------------------------------------------------------------------------
__global__ __launch_bounds__(256) void proj_tile(
    const float* __restrict__ X, const float* __restrict__ W,
    const float* __restrict__ Bias, float* __restrict__ Out, int Cout)
{
  __shared__ float xs[32][64];    // [c_local][i_local]
  __shared__ float wsm[64][33];   // [o_local][c_local] (+1 pad: kills 16-way bank conflict)
  const int b  = blockIdx.z;
  const int o0 = blockIdx.y * 64;
  const int i0 = blockIdx.x * 64;
  const int t  = threadIdx.x;
  const float* Xb = X + (size_t)b * CIN * LL;
  const int ii = (t & 15) * 4;
  const int oi = (t >> 4) * 4;
  float acc[4][4] = {{0.f,0.f,0.f,0.f},{0.f,0.f,0.f,0.f},{0.f,0.f,0.f,0.f},{0.f,0.f,0.f,0.f}};

  for (int kk = 0; kk < CIN; kk += 32) {
#pragma unroll
    for (int r = 0; r < 8; r++) {               // 2048 elems of x tile
      int idx = t + r * 256;
      int cl = idx >> 6, il = idx & 63;
      xs[cl][il] = Xb[(size_t)(kk + cl) * LL + i0 + il];
    }
#pragma unroll
    for (int r = 0; r < 8; r++) {               // 2048 elems of w tile
      int idx = t + r * 256;
      int ol = idx >> 5, cl = idx & 31;
      wsm[ol][cl] = W[(size_t)(o0 + ol) * CIN + kk + cl];
    }
    __syncthreads();
#pragma unroll
    for (int c = 0; c < 32; c++) {
      const float4 xv = *(const float4*)&xs[c][ii];
      const float w0 = wsm[oi + 0][c];
      const float w1 = wsm[oi + 1][c];
      const float w2 = wsm[oi + 2][c];
      const float w3 = wsm[oi + 3][c];
      acc[0][0] += w0 * xv.x; acc[0][1] += w0 * xv.y; acc[0][2] += w0 * xv.z; acc[0][3] += w0 * xv.w;
      acc[1][0] += w1 * xv.x; acc[1][1] += w1 * xv.y; acc[1][2] += w1 * xv.z; acc[1][3] += w1 * xv.w;
      acc[2][0] += w2 * xv.x; acc[2][1] += w2 * xv.y; acc[2][2] += w2 * xv.z; acc[2][3] += w2 * xv.w;
      acc[3][0] += w3 * xv.x; acc[3][1] += w3 * xv.y; acc[3][2] += w3 * xv.z; acc[3][3] += w3 * xv.w;
    }
    __syncthreads();
  }
#pragma unroll
  for (int o = 0; o < 4; o++) {
    const float bb = Bias[o0 + oi + o];
#pragma unroll
    for (int q = 0; q < 4; q++)
      Out[((size_t)b * Cout + o0 + oi + o) * LL + i0 + ii + q] = acc[o][q] + bb;
  }
}

// ---------------------------------------------------------------------------
// Softmax stats: for each (b,i): m = max_j q_i.k_j ; l = sum_j exp(s-m).
// Block = 256 threads = 4 waves; block handles 16 query rows (4/wave),
// staging K in 64x64 LDS tiles. Online (m,l) per lane, wave-reduce at end.
// ---------------------------------------------------------------------------
__global__ __launch_bounds__(256) void attn_stats(
    const float* __restrict__ Q, const float* __restrict__ K,
    float* __restrict__ Mx, float* __restrict__ Ls)
{
  __shared__ float qs[64][16];   // [d][i_local]
  __shared__ float ks[64][65];   // [d][j_local] (+1 pad)
  const int b  = blockIdx.z;
  const int i0 = blockIdx.x * 16;
  const int t  = threadIdx.x;
  const int jl = t & 63;
  const int wv = t >> 6;          // wave id: owns i_local 4*wv .. 4*wv+3
  const float* Qb = Q + (size_t)b * CR * LL;
  const float* Kb = K + (size_t)b * CR * LL;

#pragma unroll
  for (int r = 0; r < 4; r++) {
    int idx = t + r * 256;
    int d = idx >> 4, il = idx & 15;
    qs[d][il] = Qb[(size_t)d * LL + i0 + il];
  }
  float m[4], s[4];
#pragma unroll
  for (int r = 0; r < 4; r++) { m[r] = -INFINITY; s[r] = 0.f; }

  for (int jt = 0; jt < LL; jt += 64) {
    __syncthreads();
#pragma unroll
    for (int r = 0; r < 16; r++) {
      int idx = t + r * 256;
      int d = idx >> 6, jj = idx & 63;
      ks[d][jj] = Kb[(size_t)d * LL + jt + jj];
    }
    __syncthreads();
    float sc[4] = {0.f, 0.f, 0.f, 0.f};
#pragma unroll
    for (int d = 0; d < 64; d++) {
      const float kv = ks[d][jl];
#pragma unroll
      for (int r = 0; r < 4; r++) sc[r] += qs[d][wv * 4 + r] * kv;
    }
#pragma unroll
    for (int r = 0; r < 4; r++) {
      const float mn = fmaxf(m[r], sc[r]);
      s[r] = s[r] * __expf(m[r] - mn) + __expf(sc[r] - mn);
      m[r] = mn;
    }
  }
  // reduce (m,s) across the 64 lanes of this wave
#pragma unroll
  for (int off = 32; off > 0; off >>= 1) {
#pragma unroll
    for (int r = 0; r < 4; r++) {
      const float mo = __shfl_xor(m[r], off);
      const float so = __shfl_xor(s[r], off);
      const float mn = fmaxf(m[r], mo);
      s[r] = s[r] * __expf(m[r] - mn) + so * __expf(mo - mn);
      m[r] = mn;
    }
  }
  if (jl == 0) {
#pragma unroll
    for (int r = 0; r < 4; r++) {
      Mx[(size_t)b * LL + i0 + wv * 4 + r] = m[r];
      Ls[(size_t)b * LL + i0 + wv * 4 + r] = s[r];
    }
  }
}

// ---------------------------------------------------------------------------
// PV with score recompute: Y[b,c,i] = gamma * (1/l_i) * sum_j exp(q_i.k_j-m_i) * V[b,c,j] + X[b,c,i]
// Block tile: 128 channels x 32 queries, j-step 32. 256 threads.
// ---------------------------------------------------------------------------
__global__ __launch_bounds__(256) void attn_pv(
    const float* __restrict__ Q, const float* __restrict__ K, const float* __restrict__ V,
    const float* __restrict__ Mx, const float* __restrict__ Ls,
    const float* __restrict__ X, const float* __restrict__ Gamma,
    float* __restrict__ Y)
{
  __shared__ float qs[64][32];     // [d][i_local]
  __shared__ float ks[64][32];     // [d][j_local]
  __shared__ float vsm[128][36];   // [c_local][j_local] (pad 36: keeps float4 align, spreads banks)
  __shared__ float ps[32][36];     // [i_local][j_local]
  const int b   = blockIdx.z;
  const int i0  = blockIdx.x * 32;
  const int c0  = blockIdx.y * 128;
  const int t   = threadIdx.x;
  const int il  = t & 31;
  const int grp = t >> 5;          // 0..7
  const float* Qb = Q + (size_t)b * CR * LL;
  const float* Kb = K + (size_t)b * CR * LL;
  const float* Vb = V + (size_t)b * CIN * LL;
  const float mi   = Mx[(size_t)b * LL + i0 + il];
  const float linv = 1.0f / Ls[(size_t)b * LL + i0 + il];
  const float gamma = Gamma[0];

#pragma unroll
  for (int r = 0; r < 8; r++) {
    int idx = t + r * 256;
    int d = idx >> 5, i2 = idx & 31;
    qs[d][i2] = Qb[(size_t)d * LL + i0 + i2];
  }
  float acc[16];
#pragma unroll
  for (int r = 0; r < 16; r++) acc[r] = 0.f;

  for (int jt = 0; jt < LL; jt += 32) {
    __syncthreads();   // protects prev-tile ks/vsm/ps reads; makes qs visible on iter 0
#pragma unroll
    for (int r = 0; r < 2; r++) {
      int idx = t + r * 256;
      int d = idx >> 5, jj = idx & 31;
      ks[d][jj] = Kb[(size_t)d * LL + jt + jj];
    }
#pragma unroll
    for (int r = 0; r < 16; r++) {
      int idx = t + r * 256;
      int cl = idx >> 5, jj = idx & 31;
      vsm[cl][jj] = Vb[(size_t)(c0 + cl) * LL + jt + jj];
    }
    __syncthreads();
    // scores: thread (il, grp) computes j = grp*4 .. grp*4+3
    {
      float sc[4] = {0.f, 0.f, 0.f, 0.f};
#pragma unroll
      for (int d = 0; d < 64; d++) {
        const float qv = qs[d][il];
        const float4 kv = *(const float4*)&ks[d][grp * 4];
        sc[0] += qv * kv.x; sc[1] += qv * kv.y; sc[2] += qv * kv.z; sc[3] += qv * kv.w;
      }
#pragma unroll
      for (int q2 = 0; q2 < 4; q2++)
        ps[il][grp * 4 + q2] = __expf(sc[q2] - mi) * linv;
    }
    __syncthreads();
    // PV accumulate: thread owns (il, c = c0 + grp + 8*r) for r=0..15
#pragma unroll
    for (int j4 = 0; j4 < 8; j4++) {
      const float4 p4 = *(const float4*)&ps[il][j4 * 4];
#pragma unroll
      for (int r = 0; r < 16; r++) {
        const float4 v4 = *(const float4*)&vsm[grp + 8 * r][j4 * 4];
        acc[r] += p4.x * v4.x + p4.y * v4.y + p4.z * v4.z + p4.w * v4.w;
      }
    }
  }
  const float* Xb = X + (size_t)b * CIN * LL;
  float*       Yb = Y + (size_t)b * CIN * LL;
#pragma unroll
  for (int r = 0; r < 16; r++) {
    const size_t off = (size_t)(c0 + grp + 8 * r) * LL + i0 + il;
    Yb[off] = gamma * acc[r] + Xb[off];
  }
}

// ---------------------------------------------------------------------------
extern "C" void kernel_launch(void* const* d_in, const int* in_sizes, int n_in,
                              void* d_out, int out_size, void* d_ws, size_t ws_size,
                              hipStream_t stream) {
  const float* x  = (const float*)d_in[0];
  const float* wq = (const float*)d_in[1];
  const float* bq = (const float*)d_in[2];
  const float* wk = (const float*)d_in[3];
  const float* bk = (const float*)d_in[4];
  const float* wv = (const float*)d_in[5];
  const float* bv = (const float*)d_in[6];
  const float* gm = (const float*)d_in[7];
  float* y = (float*)d_out;

  // per-batch scratch (floats): q(64*L) + k(64*L) + v(512*L) + m(L) + l(L)
  const size_t perb_f = (size_t)(CR + CR + CIN) * LL + 2 * LL;
  int nbc = 8;
  while (nbc > 1 && ws_size < perb_f * sizeof(float) * (size_t)nbc) nbc >>= 1;

  const dim3 blk(256, 1, 1);
  for (int b0 = 0; b0 < 8; b0 += nbc) {
    const int nb = (8 - b0 < nbc) ? (8 - b0) : nbc;
    float* q  = (float*)d_ws;
    float* k  = q  + (size_t)nb * CR * LL;
    float* v  = k  + (size_t)nb * CR * LL;
    float* Mx = v  + (size_t)nb * CIN * LL;
    float* Ls = Mx + (size_t)nb * LL;
    const float* xb = x + (size_t)b0 * CIN * LL;
    float*       yb = y + (size_t)b0 * CIN * LL;

    hipLaunchKernelGGL(proj_tile, dim3(LL / 64, CR / 64, nb), blk, 0, stream, xb, wq, bq, q, CR);
    hipLaunchKernelGGL(proj_tile, dim3(LL / 64, CR / 64, nb), blk, 0, stream, xb, wk, bk, k, CR);
    hipLaunchKernelGGL(proj_tile, dim3(LL / 64, CIN / 64, nb), blk, 0, stream, xb, wv, bv, v, CIN);
    hipLaunchKernelGGL(attn_stats, dim3(LL / 16, 1, nb), blk, 0, stream, q, k, Mx, Ls);
    hipLaunchKernelGGL(attn_pv, dim3(LL / 32, CIN / 128, nb), blk, 0, stream,
                       q, k, v, Mx, Ls, xb, gm, yb);
  }
}

// Round 2
// 289.366 us; speedup vs baseline: 10.0977x; 10.0977x over previous
//
#include <hip/hip_runtime.h>
#include <cmath>

#define LL  2048
#define CIN 512
#define CR  64

typedef __bf16 bf16x8 __attribute__((ext_vector_type(8)));
typedef float f32x4 __attribute__((ext_vector_type(4)));
typedef unsigned int u32;
typedef unsigned short u16;

__device__ __forceinline__ u16 f2bf(float f) {
  u32 u = __builtin_bit_cast(unsigned int, f);
  u = (u + 0x7FFFu + ((u >> 16) & 1u)) >> 16;   // RNE
  return (u16)u;
}
__device__ __forceinline__ bf16x8 ld8(const u16* p) {
  return *reinterpret_cast<const bf16x8*>(p);
}
__device__ __forceinline__ f32x4 mfma16(bf16x8 a, bf16x8 b, f32x4 c) {
  return __builtin_amdgcn_mfma_f32_16x16x32_bf16(a, b, c, 0, 0, 0);
}

// ---------------------------------------------------------------------------
// fp32 -> bf16 convert (weights)
// ---------------------------------------------------------------------------
__global__ void cvt_f32_bf16(const float* __restrict__ s, u16* __restrict__ d, int n) {
  int i = blockIdx.x * 256 + threadIdx.x;
  if (i < n) d[i] = f2bf(s[i]);
}

// ---------------------------------------------------------------------------
// Transpose+convert: x[b][c][i] fp32 -> xT[b][i][c] bf16. 64x64 LDS tile.
// ---------------------------------------------------------------------------
__global__ __launch_bounds__(256) void xpose(const float* __restrict__ X, u16* __restrict__ xT) {
  __shared__ u16 tile[64][66];
  const int bb = blockIdx.z;
  const int c0 = blockIdx.y * 64;
  const int i0 = blockIdx.x * 64;
  const int t  = threadIdx.x;
  const float* Xb = X + (size_t)bb * CIN * LL;
#pragma unroll
  for (int r = 0; r < 16; r++) {
    int idx = t + r * 256;
    int c = idx >> 6, i = idx & 63;
    tile[c][i] = f2bf(Xb[(size_t)(c0 + c) * LL + i0 + i]);
  }
  __syncthreads();
  u16* out = xT + (size_t)bb * LL * CIN;
#pragma unroll
  for (int r = 0; r < 8; r++) {
    int idx = t + r * 256;
    int i = idx >> 5, cp = idx & 31;             // cp = c-pair
    u32 pk = (u32)tile[2 * cp][i] | ((u32)tile[2 * cp + 1][i] << 16);
    *(u32*)(out + (size_t)(i0 + i) * CIN + c0 + 2 * cp) = pk;
  }
}

// ---------------------------------------------------------------------------
// Q,K projections (fused): qT[i][o], kT[i][o] = sum_c xT[i][c]*W[o][c] + bias
// Grid (LL/32, 1, nb), 256 thr. Wave w: proj = w>>1 (q/k), o-half = (w&1)*32.
// LDS-free: fragments straight from L2.
// ---------------------------------------------------------------------------
__global__ __launch_bounds__(256, 2) void proj_qk(
    const u16* __restrict__ xT, const u16* __restrict__ wqb, const u16* __restrict__ wkb,
    const float* __restrict__ bq, const float* __restrict__ bk,
    u16* __restrict__ qT, u16* __restrict__ kT)
{
  const int bb = blockIdx.z;
  const int i0 = blockIdx.x * 32;
  const int t  = threadIdx.x;
  const int w  = t >> 6, l = t & 63;
  const int li = l & 15, g = l >> 4;
  const int proj = w >> 1;
  const int oh = (w & 1) * 32;
  const u16* W  = proj ? wkb : wqb;
  const float* Bs = proj ? bk : bq;
  u16* Out = (proj ? kT : qT) + (size_t)bb * LL * CR;
  const u16* xTb = xT + (size_t)bb * LL * CIN;

  f32x4 acc[2][2];
#pragma unroll
  for (int mt = 0; mt < 2; mt++)
#pragma unroll
    for (int nt = 0; nt < 2; nt++) acc[mt][nt] = f32x4{0.f, 0.f, 0.f, 0.f};

  for (int c0 = 0; c0 < CIN; c0 += 32) {
    bf16x8 af[2], bfr[2];
#pragma unroll
    for (int mt = 0; mt < 2; mt++)
      af[mt] = ld8(xTb + (size_t)(i0 + mt * 16 + li) * CIN + c0 + g * 8);
#pragma unroll
    for (int nt = 0; nt < 2; nt++)
      bfr[nt] = ld8(W + (size_t)(oh + nt * 16 + li) * CIN + c0 + g * 8);
#pragma unroll
    for (int mt = 0; mt < 2; mt++)
#pragma unroll
      for (int nt = 0; nt < 2; nt++)
        acc[mt][nt] = mfma16(af[mt], bfr[nt], acc[mt][nt]);
  }
#pragma unroll
  for (int mt = 0; mt < 2; mt++)
#pragma unroll
    for (int nt = 0; nt < 2; nt++) {
      const int o = oh + nt * 16 + li;
      const float bias = Bs[o];
#pragma unroll
      for (int r = 0; r < 4; r++) {
        const int i = i0 + mt * 16 + g * 4 + r;
        Out[(size_t)i * CR + o] = f2bf(acc[mt][nt][r] + bias);
      }
    }
}

// ---------------------------------------------------------------------------
// V projection: v[o][i] = sum_c Wv[o][c]*xT[i][c] + bv[o]   (M=o, N=i)
// Grid (LL/64, CIN/64, nb), 256 thr; wave w owns i-quarter w*16, o 0..63.
// ---------------------------------------------------------------------------
__global__ __launch_bounds__(256, 2) void proj_v(
    const u16* __restrict__ xT, const u16* __restrict__ wvb,
    const float* __restrict__ bv, u16* __restrict__ V)
{
  const int bb = blockIdx.z;
  const int i0 = blockIdx.x * 64;
  const int o0 = blockIdx.y * 64;
  const int t  = threadIdx.x;
  const int w  = t >> 6, l = t & 63;
  const int li = l & 15, g = l >> 4;
  const int iq = w * 16;
  const u16* xTb = xT + (size_t)bb * LL * CIN;
  u16* Vb = V + (size_t)bb * CIN * LL;

  f32x4 acc[4];
#pragma unroll
  for (int mt = 0; mt < 4; mt++) acc[mt] = f32x4{0.f, 0.f, 0.f, 0.f};

  for (int c0 = 0; c0 < CIN; c0 += 32) {
    bf16x8 bfr = ld8(xTb + (size_t)(i0 + iq + li) * CIN + c0 + g * 8);
#pragma unroll
    for (int mt = 0; mt < 4; mt++) {
      bf16x8 af = ld8(wvb + (size_t)(o0 + mt * 16 + li) * CIN + c0 + g * 8);
      acc[mt] = mfma16(af, bfr, acc[mt]);
    }
  }
  const int i = i0 + iq + li;
#pragma unroll
  for (int mt = 0; mt < 4; mt++)
#pragma unroll
    for (int r = 0; r < 4; r++) {
      const int o = o0 + mt * 16 + g * 4 + r;
      Vb[(size_t)o * LL + i] = f2bf(acc[mt][r] + bv[o]);
    }
}

// ---------------------------------------------------------------------------
// Flash attention + epilogue: Y = gamma * softmax(Q^T K) V^T + X
// Grid (LL/32, 1, nb), 256 thr = 4 waves. Wave w: all 32 queries x 128 chans.
// No __syncthreads in the j-loop; per-wave P buffer in LDS.
// ---------------------------------------------------------------------------
__global__ __launch_bounds__(256, 2) void attn_mfma(
    const u16* __restrict__ qT, const u16* __restrict__ kT, const u16* __restrict__ v,
    const float* __restrict__ X, const float* __restrict__ Gamma, float* __restrict__ Y)
{
  __shared__ u16 P[4][32][40];     // per-wave P tile [i][j], stride 80B (16B-aligned)
  const int bb = blockIdx.z;
  const int i0 = blockIdx.x * 32;
  const int t  = threadIdx.x;
  const int w  = t >> 6, l = t & 63;
  const int li = l & 15, g = l >> 4;
  const int c0 = w * 128;
  const u16* qTb = qT + (size_t)bb * LL * CR;
  const u16* kTb = kT + (size_t)bb * LL * CR;
  const u16* vb  = v  + (size_t)bb * CIN * LL;

  // Q fragments (persistent): B^T = Q^T[i][d]
  bf16x8 qf[2][2];
#pragma unroll
  for (int nt = 0; nt < 2; nt++)
#pragma unroll
    for (int kk = 0; kk < 2; kk++)
      qf[nt][kk] = ld8(qTb + (size_t)(i0 + nt * 16 + li) * CR + kk * 32 + g * 8);

  f32x4 acc[8][2];
#pragma unroll
  for (int mC = 0; mC < 8; mC++)
#pragma unroll
    for (int nt = 0; nt < 2; nt++) acc[mC][nt] = f32x4{0.f, 0.f, 0.f, 0.f};
  float m[2] = {-INFINITY, -INFINITY};
  float lsum[2] = {0.f, 0.f};

  for (int jt = 0; jt < LL; jt += 32) {
    // K fragments: A = K^T[j][d]
    bf16x8 kf[2][2];
#pragma unroll
    for (int mt = 0; mt < 2; mt++)
#pragma unroll
      for (int kk = 0; kk < 2; kk++)
        kf[mt][kk] = ld8(kTb + (size_t)(jt + mt * 16 + li) * CR + kk * 32 + g * 8);
    // V fragments: A = V[c][j]
    bf16x8 vf[8];
#pragma unroll
    for (int mC = 0; mC < 8; mC++)
      vf[mC] = ld8(vb + (size_t)(c0 + mC * 16 + li) * LL + jt + g * 8);

    // S^T[j][i] = sum_d K^T[j][d] * Q[d][i]
    f32x4 s[2][2];
#pragma unroll
    for (int mt = 0; mt < 2; mt++)
#pragma unroll
      for (int nt = 0; nt < 2; nt++) {
        s[mt][nt] = mfma16(kf[mt][0], qf[nt][0], f32x4{0.f, 0.f, 0.f, 0.f});
        s[mt][nt] = mfma16(kf[mt][1], qf[nt][1], s[mt][nt]);
      }

    // column (per-i) max over the 32 j of this tile
    float pmax[2];
#pragma unroll
    for (int nt = 0; nt < 2; nt++) {
      float mx = s[0][nt][0];
#pragma unroll
      for (int mt = 0; mt < 2; mt++)
#pragma unroll
        for (int r = 0; r < 4; r++) mx = fmaxf(mx, s[mt][nt][r]);
      mx = fmaxf(mx, __shfl_xor(mx, 16));
      mx = fmaxf(mx, __shfl_xor(mx, 32));
      pmax[nt] = mx;
    }
    const int noresc = __all(pmax[0] <= m[0] && pmax[1] <= m[1]);
    if (!noresc) {
      float rs[2];
#pragma unroll
      for (int nt = 0; nt < 2; nt++) {
        const float mn = fmaxf(m[nt], pmax[nt]);
        rs[nt] = __expf(m[nt] - mn);
        lsum[nt] *= rs[nt];
        m[nt] = mn;
      }
#pragma unroll
      for (int mC = 0; mC < 8; mC++)
#pragma unroll
        for (int nt = 0; nt < 2; nt++) {
#pragma unroll
          for (int r = 0; r < 4; r++) acc[mC][nt][r] *= rs[nt];
        }
    }
    // P = exp(S - m), row-sum into lsum, pack bf16 into per-wave LDS
    float rsum[2] = {0.f, 0.f};
    float p[2][2][4];
#pragma unroll
    for (int mt = 0; mt < 2; mt++)
#pragma unroll
      for (int nt = 0; nt < 2; nt++)
#pragma unroll
        for (int r = 0; r < 4; r++) {
          const float e = __expf(s[mt][nt][r] - m[nt]);
          p[mt][nt][r] = e;
          rsum[nt] += e;
        }
#pragma unroll
    for (int nt = 0; nt < 2; nt++) {
      float rsn = rsum[nt];
      rsn += __shfl_xor(rsn, 16);
      rsn += __shfl_xor(rsn, 32);
      lsum[nt] += rsn;
    }
#pragma unroll
    for (int mt = 0; mt < 2; mt++)
#pragma unroll
      for (int nt = 0; nt < 2; nt++)
#pragma unroll
        for (int e = 0; e < 2; e++) {
          u32 pk = (u32)f2bf(p[mt][nt][2 * e]) | ((u32)f2bf(p[mt][nt][2 * e + 1]) << 16);
          *(u32*)(&P[w][nt * 16 + li][mt * 16 + g * 4 + 2 * e]) = pk;
        }
    // PV: B^T = P[i][j] (compiler inserts lgkmcnt wait on the dependency)
    bf16x8 pf[2];
#pragma unroll
    for (int nt = 0; nt < 2; nt++)
      pf[nt] = ld8(&P[w][nt * 16 + li][g * 8]);
#pragma unroll
    for (int mC = 0; mC < 8; mC++)
#pragma unroll
      for (int nt = 0; nt < 2; nt++)
        acc[mC][nt] = mfma16(vf[mC], pf[nt], acc[mC][nt]);
  }

  // epilogue: Y = gamma * acc / l + X
  const float gamma = Gamma[0];
  const float linv[2] = {1.0f / lsum[0], 1.0f / lsum[1]};
  const float* Xb = X + (size_t)bb * CIN * LL;
  float*       Yb = Y + (size_t)bb * CIN * LL;
#pragma unroll
  for (int mC = 0; mC < 8; mC++)
#pragma unroll
    for (int nt = 0; nt < 2; nt++)
#pragma unroll
      for (int r = 0; r < 4; r++) {
        const int c = c0 + mC * 16 + g * 4 + r;
        const int i = i0 + nt * 16 + li;
        const size_t off = (size_t)c * LL + i;
        Yb[off] = gamma * acc[mC][nt][r] * linv[nt] + Xb[off];
      }
}

// ---------------------------------------------------------------------------
extern "C" void kernel_launch(void* const* d_in, const int* in_sizes, int n_in,
                              void* d_out, int out_size, void* d_ws, size_t ws_size,
                              hipStream_t stream) {
  const float* x  = (const float*)d_in[0];
  const float* wq = (const float*)d_in[1];
  const float* bq = (const float*)d_in[2];
  const float* wk = (const float*)d_in[3];
  const float* bk = (const float*)d_in[4];
  const float* wv = (const float*)d_in[5];
  const float* bv = (const float*)d_in[6];
  const float* gm = (const float*)d_in[7];
  float* y = (float*)d_out;

  u16* wqb = (u16*)d_ws;
  u16* wkb = wqb + (size_t)CR * CIN;
  u16* wvb = wkb + (size_t)CR * CIN;
  u16* dyn = wvb + (size_t)CIN * CIN;
  const size_t wbytes = ((size_t)2 * CR * CIN + (size_t)CIN * CIN) * 2;
  // per-batch dynamic scratch (u16): xT + qT + kT + v
  const size_t perb = ((size_t)LL * CIN + 2 * (size_t)LL * CR + (size_t)CIN * LL);
  int nbc = 8;
  while (nbc > 1 && ws_size < wbytes + perb * 2 * (size_t)nbc) nbc >>= 1;

  const dim3 blk(256, 1, 1);
  hipLaunchKernelGGL(cvt_f32_bf16, dim3((CR * CIN + 255) / 256), blk, 0, stream, wq, wqb, CR * CIN);
  hipLaunchKernelGGL(cvt_f32_bf16, dim3((CR * CIN + 255) / 256), blk, 0, stream, wk, wkb, CR * CIN);
  hipLaunchKernelGGL(cvt_f32_bf16, dim3((CIN * CIN + 255) / 256), blk, 0, stream, wv, wvb, CIN * CIN);

  for (int b0 = 0; b0 < 8; b0 += nbc) {
    const int nb = (8 - b0 < nbc) ? (8 - b0) : nbc;
    u16* xT = dyn;
    u16* qT = xT + (size_t)nb * LL * CIN;
    u16* kT = qT + (size_t)nb * LL * CR;
    u16* vB = kT + (size_t)nb * LL * CR;
    const float* xb = x + (size_t)b0 * CIN * LL;
    float*       yb = y + (size_t)b0 * CIN * LL;

    hipLaunchKernelGGL(xpose, dim3(LL / 64, CIN / 64, nb), blk, 0, stream, xb, xT);
    hipLaunchKernelGGL(proj_qk, dim3(LL / 32, 1, nb), blk, 0, stream, xT, wqb, wkb, bq, bk, qT, kT);
    hipLaunchKernelGGL(proj_v, dim3(LL / 64, CIN / 64, nb), blk, 0, stream, xT, wvb, bv, vB);
    hipLaunchKernelGGL(attn_mfma, dim3(LL / 32, 1, nb), blk, 0, stream, qT, kT, vB, xb, gm, yb);
  }
}

// Round 3
// 251.591 us; speedup vs baseline: 11.6139x; 1.1501x over previous
//
#include <hip/hip_runtime.h>
#include <cmath>

#define LL  2048
#define CIN 512
#define CR  64

typedef __bf16 bf16x8 __attribute__((ext_vector_type(8)));
typedef float f32x4 __attribute__((ext_vector_type(4)));
typedef unsigned int u32;
typedef unsigned short u16;
typedef unsigned long long u64;

__device__ __forceinline__ u16 f2bf(float f) {
  return __builtin_bit_cast(u16, (__bf16)f);   // native v_cvt path
}
__device__ __forceinline__ bf16x8 ld8(const u16* p) {
  return *reinterpret_cast<const bf16x8*>(p);
}
__device__ __forceinline__ f32x4 mfma16(bf16x8 a, bf16x8 b, f32x4 c) {
  return __builtin_amdgcn_mfma_f32_16x16x32_bf16(a, b, c, 0, 0, 0);
}
// P tile address: row-major [32][128] u16 (256 B rows), 16B-slot XOR swizzle by row
__device__ __forceinline__ u16* pp(u16* base, int row, int col) {
  u32 off = ((u32)row << 8) + ((u32)col << 1);
  off ^= ((u32)(row & 7) << 4);
  return (u16*)((char*)base + off);
}

// ---------------------------------------------------------------------------
__global__ void cvt_f32_bf16(const float* __restrict__ s, u16* __restrict__ d, int n) {
  int i = blockIdx.x * 256 + threadIdx.x;
  if (i < n) d[i] = f2bf(s[i]);
}

// ---------------------------------------------------------------------------
// Transpose+convert: x[b][c][i] fp32 -> xT[b][i][c] bf16. 64x64 LDS tile.
// ---------------------------------------------------------------------------
__global__ __launch_bounds__(256) void xpose(const float* __restrict__ X, u16* __restrict__ xT) {
  __shared__ u16 tile[64][66];
  const int bb = blockIdx.z;
  const int c0 = blockIdx.y * 64;
  const int i0 = blockIdx.x * 64;
  const int t  = threadIdx.x;
  const float* Xb = X + (size_t)bb * CIN * LL;
#pragma unroll
  for (int r = 0; r < 16; r++) {
    int idx = t + r * 256;
    int c = idx >> 6, i = idx & 63;
    tile[c][i] = f2bf(Xb[(size_t)(c0 + c) * LL + i0 + i]);
  }
  __syncthreads();
  u16* out = xT + (size_t)bb * LL * CIN;
#pragma unroll
  for (int r = 0; r < 8; r++) {
    int idx = t + r * 256;
    int i = idx >> 5, cp = idx & 31;
    u32 pk = (u32)tile[2 * cp][i] | ((u32)tile[2 * cp + 1][i] << 16);
    *(u32*)(out + (size_t)(i0 + i) * CIN + c0 + 2 * cp) = pk;
  }
}

// ---------------------------------------------------------------------------
// Q,K projections (fused): qT[i][o], kT[i][o]
// ---------------------------------------------------------------------------
__global__ __launch_bounds__(256, 2) void proj_qk(
    const u16* __restrict__ xT, const u16* __restrict__ wqb, const u16* __restrict__ wkb,
    const float* __restrict__ bq, const float* __restrict__ bk,
    u16* __restrict__ qT, u16* __restrict__ kT)
{
  const int bb = blockIdx.z;
  const int i0 = blockIdx.x * 32;
  const int t  = threadIdx.x;
  const int w  = t >> 6, l = t & 63;
  const int li = l & 15, g = l >> 4;
  const int proj = w >> 1;
  const int oh = (w & 1) * 32;
  const u16* W  = proj ? wkb : wqb;
  const float* Bs = proj ? bk : bq;
  u16* Out = (proj ? kT : qT) + (size_t)bb * LL * CR;
  const u16* xTb = xT + (size_t)bb * LL * CIN;

  f32x4 acc[2][2];
#pragma unroll
  for (int mt = 0; mt < 2; mt++)
#pragma unroll
    for (int nt = 0; nt < 2; nt++) acc[mt][nt] = f32x4{0.f, 0.f, 0.f, 0.f};

  for (int c0 = 0; c0 < CIN; c0 += 32) {
    bf16x8 af[2], bfr[2];
#pragma unroll
    for (int mt = 0; mt < 2; mt++)
      af[mt] = ld8(xTb + (size_t)(i0 + mt * 16 + li) * CIN + c0 + g * 8);
#pragma unroll
    for (int nt = 0; nt < 2; nt++)
      bfr[nt] = ld8(W + (size_t)(oh + nt * 16 + li) * CIN + c0 + g * 8);
#pragma unroll
    for (int mt = 0; mt < 2; mt++)
#pragma unroll
      for (int nt = 0; nt < 2; nt++)
        acc[mt][nt] = mfma16(af[mt], bfr[nt], acc[mt][nt]);
  }
#pragma unroll
  for (int mt = 0; mt < 2; mt++)
#pragma unroll
    for (int nt = 0; nt < 2; nt++) {
      const int o = oh + nt * 16 + li;
      const float bias = Bs[o];
#pragma unroll
      for (int r = 0; r < 4; r++) {
        const int i = i0 + mt * 16 + g * 4 + r;
        Out[(size_t)i * CR + o] = f2bf(acc[mt][nt][r] + bias);
      }
    }
}

// ---------------------------------------------------------------------------
// V projection: v[o][i]
// ---------------------------------------------------------------------------
__global__ __launch_bounds__(256, 2) void proj_v(
    const u16* __restrict__ xT, const u16* __restrict__ wvb,
    const float* __restrict__ bv, u16* __restrict__ V)
{
  const int bb = blockIdx.z;
  const int i0 = blockIdx.x * 64;
  const int o0 = blockIdx.y * 64;
  const int t  = threadIdx.x;
  const int w  = t >> 6, l = t & 63;
  const int li = l & 15, g = l >> 4;
  const int iq = w * 16;
  const u16* xTb = xT + (size_t)bb * LL * CIN;
  u16* Vb = V + (size_t)bb * CIN * LL;

  f32x4 acc[4];
#pragma unroll
  for (int mt = 0; mt < 4; mt++) acc[mt] = f32x4{0.f, 0.f, 0.f, 0.f};

  for (int c0 = 0; c0 < CIN; c0 += 32) {
    bf16x8 bfr = ld8(xTb + (size_t)(i0 + iq + li) * CIN + c0 + g * 8);
#pragma unroll
    for (int mt = 0; mt < 4; mt++) {
      bf16x8 af = ld8(wvb + (size_t)(o0 + mt * 16 + li) * CIN + c0 + g * 8);
      acc[mt] = mfma16(af, bfr, acc[mt]);
    }
  }
  const int i = i0 + iq + li;
#pragma unroll
  for (int mt = 0; mt < 4; mt++)
#pragma unroll
    for (int r = 0; r < 4; r++) {
      const int o = o0 + mt * 16 + g * 4 + r;
      Vb[(size_t)o * LL + i] = f2bf(acc[mt][r] + bv[o]);
    }
}

// ---------------------------------------------------------------------------
// Flash attention + epilogue. Grid (64*nb), 256 thr = 4 waves.
// Macro-iter = 128 j: wave w computes S^T for j-subtile w (no redundancy);
// cross-wave max via LDS; P (bf16) in XOR-swizzled LDS; l via ones-MFMA;
// PV: each wave 128 channels x all 128 j. 2 barriers / 128 j.
// ---------------------------------------------------------------------------
__device__ __forceinline__ void vload(bf16x8* vf, const u16* vb, int c0, int li, int g, int joff) {
#pragma unroll
  for (int mC = 0; mC < 8; mC++)
    vf[mC] = ld8(vb + (size_t)(c0 + mC * 16 + li) * LL + joff + g * 8);
}

__device__ __forceinline__ void pv_step(u16* Pls, int li, int g, int ks,
                                        const bf16x8* vf, bf16x8 onef,
                                        f32x4 acc[8][2], f32x4* lacc) {
  bf16x8 pf0 = ld8(pp(Pls, li,      ks * 32 + g * 8));
  bf16x8 pf1 = ld8(pp(Pls, 16 + li, ks * 32 + g * 8));
  lacc[0] = mfma16(onef, pf0, lacc[0]);
  lacc[1] = mfma16(onef, pf1, lacc[1]);
  __builtin_amdgcn_s_setprio(1);
#pragma unroll
  for (int mC = 0; mC < 8; mC++) {
    acc[mC][0] = mfma16(vf[mC], pf0, acc[mC][0]);
    acc[mC][1] = mfma16(vf[mC], pf1, acc[mC][1]);
  }
  __builtin_amdgcn_s_setprio(0);
}

__global__ __launch_bounds__(256, 2) void attn_mfma(
    const u16* __restrict__ qT, const u16* __restrict__ kT, const u16* __restrict__ v,
    const float* __restrict__ X, const float* __restrict__ Gamma, float* __restrict__ Y,
    int nb)
{
  __shared__ u16 Pls[32 * 128];      // 8 KB, swizzled
  __shared__ float pmaxb[4][32];
  const int bid = blockIdx.x;
  const int bb  = bid % nb;          // batch == XCD (when nb==8): K/V stay in one L2
  const int i0  = (bid / nb) * 32;
  const int t   = threadIdx.x;
  const int w   = t >> 6, l = t & 63;
  const int li  = l & 15, g = l >> 4;
  const int c0  = w * 128;
  const u16* qTb = qT + (size_t)bb * LL * CR;
  const u16* kTb = kT + (size_t)bb * LL * CR;
  const u16* vb  = v  + (size_t)bb * CIN * LL;

  bf16x8 qf[2][2];
#pragma unroll
  for (int nt = 0; nt < 2; nt++)
#pragma unroll
    for (int kk = 0; kk < 2; kk++)
      qf[nt][kk] = ld8(qTb + (size_t)(i0 + nt * 16 + li) * CR + kk * 32 + g * 8);

  bf16x8 onef;
#pragma unroll
  for (int e = 0; e < 8; e++) onef[e] = (__bf16)1.0f;

  f32x4 acc[8][2];
#pragma unroll
  for (int mC = 0; mC < 8; mC++)
#pragma unroll
    for (int nt = 0; nt < 2; nt++) acc[mC][nt] = f32x4{0.f, 0.f, 0.f, 0.f};
  f32x4 lacc[2] = {f32x4{0.f,0.f,0.f,0.f}, f32x4{0.f,0.f,0.f,0.f}};
  float m[2] = {-INFINITY, -INFINITY};

  bf16x8 va[8], vb2[8];

  for (int jt = 0; jt < LL; jt += 128) {
    // ---- phase A: this wave's 32x32 S^T subtile ----
    const int jw = jt + w * 32;
    bf16x8 kf[2][2];
#pragma unroll
    for (int mt = 0; mt < 2; mt++)
#pragma unroll
      for (int kk = 0; kk < 2; kk++)
        kf[mt][kk] = ld8(kTb + (size_t)(jw + mt * 16 + li) * CR + kk * 32 + g * 8);
    f32x4 s[2][2];
#pragma unroll
    for (int mt = 0; mt < 2; mt++)
#pragma unroll
      for (int nt = 0; nt < 2; nt++) {
        s[mt][nt] = mfma16(kf[mt][0], qf[nt][0], f32x4{0.f, 0.f, 0.f, 0.f});
        s[mt][nt] = mfma16(kf[mt][1], qf[nt][1], s[mt][nt]);
      }
    float pmax[2];
#pragma unroll
    for (int nt = 0; nt < 2; nt++) {
      float mx = s[0][nt][0];
#pragma unroll
      for (int mt = 0; mt < 2; mt++)
#pragma unroll
        for (int r = 0; r < 4; r++) mx = fmaxf(mx, s[mt][nt][r]);
      mx = fmaxf(mx, __shfl_xor(mx, 16));
      mx = fmaxf(mx, __shfl_xor(mx, 32));
      pmax[nt] = mx;
    }
    if (g == 0) { pmaxb[w][li] = pmax[0]; pmaxb[w][16 + li] = pmax[1]; }
    __syncthreads();   // barrier 1: pmax visible; also fences P reuse (see below)
    float mn[2];
#pragma unroll
    for (int nt = 0; nt < 2; nt++) {
      const int i = nt * 16 + li;
      float t0 = fmaxf(fmaxf(pmaxb[0][i], pmaxb[1][i]), fmaxf(pmaxb[2][i], pmaxb[3][i]));
      mn[nt] = fmaxf(m[nt], t0);
    }
    if (!__all((mn[0] <= m[0]) && (mn[1] <= m[1]))) {
      float rs[2] = {__expf(m[0] - mn[0]), __expf(m[1] - mn[1])};
#pragma unroll
      for (int mC = 0; mC < 8; mC++)
#pragma unroll
        for (int nt = 0; nt < 2; nt++)
#pragma unroll
          for (int r = 0; r < 4; r++) acc[mC][nt][r] *= rs[nt];
#pragma unroll
      for (int nt = 0; nt < 2; nt++)
#pragma unroll
        for (int r = 0; r < 4; r++) lacc[nt][r] *= rs[nt];
    }
    m[0] = mn[0]; m[1] = mn[1];

    // ---- phase B: exp, pack bf16, store this wave's P subtile ----
#pragma unroll
    for (int mt = 0; mt < 2; mt++) {
      const int colb = w * 32 + mt * 16 + g * 4;
#pragma unroll
      for (int nt = 0; nt < 2; nt++) {
        const float e0 = __expf(s[mt][nt][0] - m[nt]);
        const float e1 = __expf(s[mt][nt][1] - m[nt]);
        const float e2 = __expf(s[mt][nt][2] - m[nt]);
        const float e3 = __expf(s[mt][nt][3] - m[nt]);
        u32 lo = (u32)f2bf(e0) | ((u32)f2bf(e1) << 16);
        u32 hi = (u32)f2bf(e2) | ((u32)f2bf(e3) << 16);
        *(u64*)pp(Pls, nt * 16 + li, colb) = ((u64)hi << 32) | lo;
      }
    }
    // prefetch V for ks=0,1 (independent of P)
    vload(va,  vb, c0, li, g, jt);
    vload(vb2, vb, c0, li, g, jt + 32);
    __syncthreads();   // barrier 2: all P subtiles written

    // ---- phase C: PV over all 128 j ----
    pv_step(Pls, li, g, 0, va,  onef, acc, lacc);
    vload(va,  vb, c0, li, g, jt + 64);
    pv_step(Pls, li, g, 1, vb2, onef, acc, lacc);
    vload(vb2, vb, c0, li, g, jt + 96);
    pv_step(Pls, li, g, 2, va,  onef, acc, lacc);
    pv_step(Pls, li, g, 3, vb2, onef, acc, lacc);
    // next iter's P writes happen only after barrier 1 -> no extra barrier here
  }

  const float gamma = Gamma[0];
  const float linv[2] = {1.0f / lacc[0][0], 1.0f / lacc[1][0]};
  const float* Xb = X + (size_t)bb * CIN * LL;
  float*       Yb = Y + (size_t)bb * CIN * LL;
#pragma unroll
  for (int mC = 0; mC < 8; mC++)
#pragma unroll
    for (int nt = 0; nt < 2; nt++)
#pragma unroll
      for (int r = 0; r < 4; r++) {
        const int c = c0 + mC * 16 + g * 4 + r;
        const int i = i0 + nt * 16 + li;
        const size_t off = (size_t)c * LL + i;
        Yb[off] = gamma * acc[mC][nt][r] * linv[nt] + Xb[off];
      }
}

// ---------------------------------------------------------------------------
extern "C" void kernel_launch(void* const* d_in, const int* in_sizes, int n_in,
                              void* d_out, int out_size, void* d_ws, size_t ws_size,
                              hipStream_t stream) {
  const float* x  = (const float*)d_in[0];
  const float* wq = (const float*)d_in[1];
  const float* bq = (const float*)d_in[2];
  const float* wk = (const float*)d_in[3];
  const float* bk = (const float*)d_in[4];
  const float* wv = (const float*)d_in[5];
  const float* bv = (const float*)d_in[6];
  const float* gm = (const float*)d_in[7];
  float* y = (float*)d_out;

  u16* wqb = (u16*)d_ws;
  u16* wkb = wqb + (size_t)CR * CIN;
  u16* wvb = wkb + (size_t)CR * CIN;
  u16* dyn = wvb + (size_t)CIN * CIN;
  const size_t wbytes = ((size_t)2 * CR * CIN + (size_t)CIN * CIN) * 2;
  const size_t perb = ((size_t)LL * CIN + 2 * (size_t)LL * CR + (size_t)CIN * LL);
  int nbc = 8;
  while (nbc > 1 && ws_size < wbytes + perb * 2 * (size_t)nbc) nbc >>= 1;

  const dim3 blk(256, 1, 1);
  hipLaunchKernelGGL(cvt_f32_bf16, dim3((CR * CIN + 255) / 256), blk, 0, stream, wq, wqb, CR * CIN);
  hipLaunchKernelGGL(cvt_f32_bf16, dim3((CR * CIN + 255) / 256), blk, 0, stream, wk, wkb, CR * CIN);
  hipLaunchKernelGGL(cvt_f32_bf16, dim3((CIN * CIN + 255) / 256), blk, 0, stream, wv, wvb, CIN * CIN);

  for (int b0 = 0; b0 < 8; b0 += nbc) {
    const int nb = (8 - b0 < nbc) ? (8 - b0) : nbc;
    u16* xT = dyn;
    u16* qT = xT + (size_t)nb * LL * CIN;
    u16* kT = qT + (size_t)nb * LL * CR;
    u16* vB = kT + (size_t)nb * LL * CR;
    const float* xb = x + (size_t)b0 * CIN * LL;
    float*       yb = y + (size_t)b0 * CIN * LL;

    hipLaunchKernelGGL(xpose, dim3(LL / 64, CIN / 64, nb), blk, 0, stream, xb, xT);
    hipLaunchKernelGGL(proj_qk, dim3(LL / 32, 1, nb), blk, 0, stream, xT, wqb, wkb, bq, bk, qT, kT);
    hipLaunchKernelGGL(proj_v, dim3(LL / 64, CIN / 64, nb), blk, 0, stream, xT, wvb, bv, vB);
    hipLaunchKernelGGL(attn_mfma, dim3(64 * nb, 1, 1), blk, 0, stream, qT, kT, vB, xb, gm, yb, nb);
  }
}